// Round 10
// baseline (1051.683 us; speedup 1.0000x reference)
//
#include <hip/hip_runtime.h>

typedef unsigned short u16;
typedef unsigned int   u32;
typedef __attribute__((ext_vector_type(8))) short bf16x8;
typedef __attribute__((ext_vector_type(4))) float f32x4;

#define DEVFN __device__ __forceinline__
#define GRID 768

DEVFN float b2f(u16 u){ u32 t=((u32)u)<<16; float f; __builtin_memcpy(&f,&t,4); return f; }
DEVFN u16 f2b(float f){ u32 t; __builtin_memcpy(&t,&f,4); t += 0x7fffu + ((t>>16)&1u); return (u16)(t>>16); }
DEVFN u32 pk2(float a, float b){ return (u32)f2b(a) | ((u32)f2b(b)<<16); }

// row -> (j,i) for upper-triangle pairs j<=i, N=89; base(j) = j*(179-j)/2
DEVFN void row2ji(int row, int* jj, int* ii){
  int j = (int)((179.0f - sqrtf(179.0f*179.0f - 8.0f*(float)row)) * 0.5f);
  if(j < 0) j = 0; if(j > 88) j = 88;
  while(j < 88 && (j+1)*(179-(j+1))/2 <= row) j++;
  while(j > 0 && j*(179-j)/2 > row) j--;
  *jj = j;
  *ii = j + (row - j*(179-j)/2);
}

struct TrArgs { const float* src; u16* dst; int C; };
struct TrPack { TrArgs a[6]; };

// ---------- grid barrier: all GRID blocks arrive; fences give cross-XCD visibility
DEVFN void gbar(u32* cnt, u32 target){
  __syncthreads();                       // drains vmcnt for all waves in block
  if(threadIdx.x == 0){
    __threadfence();                     // release: wb dirty L2 (agent scope)
    __hip_atomic_fetch_add(cnt, 1u, __ATOMIC_RELEASE, __HIP_MEMORY_SCOPE_AGENT);
    while(__hip_atomic_load(cnt, __ATOMIC_ACQUIRE, __HIP_MEMORY_SCOPE_AGENT) < target)
      __builtin_amdgcn_s_sleep(8);
    __threadfence();                     // acquire: inv L1/L2 stale lines
  }
  __syncthreads();
}

// ---------- prep body: virtual-block id space
// [0,6144) weight transposes ; [6144,6176) logit zero ; [6176,6888) d_out zero
// [6888,23272) pgen pairs: 2 rows per id, 16B stores
DEVFN void prep_body(const TrPack& pk, float* __restrict__ logit, float* __restrict__ dout,
                     const float* __restrict__ x, u16* __restrict__ pbuf, long pz,
                     int id, int tid, u16* tile /*32*33 u16*/){
  if(id < 6144){
    TrArgs t = pk.a[id>>10];
    int q = id & 1023;
    int bx = (q&31)*32, by = (q>>5)*32;
    if(bx < t.C){
      int tx = tid&31, ty = tid>>5;
      #pragma unroll
      for(int yy=ty; yy<32; yy+=8) tile[yy*33+tx] = f2b(t.src[(size_t)(by+yy)*t.C + bx+tx]);
      __syncthreads();
      #pragma unroll
      for(int yy=ty; yy<32; yy+=8) t.dst[(size_t)(bx+yy)*1024 + by+tx] = tile[tx*33+yy];
      __syncthreads();
    }
  } else if(id < 6176){
    int idx = (id-6144)*1024 + tid*4;
    *(float4*)(logit + idx) = (float4){0.f,0.f,0.f,0.f};
  } else if(id < 6888){
    int idx = (id-6176)*1024 + tid*4;
    *(float4*)(dout + idx) = (float4){0.f,0.f,0.f,0.f};
  } else {
    int pid = id - 6888;
    int z = pid >> 11, rp = pid & 2047;
    int half = tid >> 7, t7 = tid & 127;
    int row = rp*2 + half;
    int j, i; row2ji(row < 4005 ? row : 0, &j, &i);
    const float* xb = x + (size_t)z*91136;
    int c = t7*8;
    float4 a0 = *(const float4*)(xb + (size_t)j*1024 + c);
    float4 a1 = *(const float4*)(xb + (size_t)j*1024 + c + 4);
    float4 b0 = *(const float4*)(xb + (size_t)i*1024 + c);
    float4 b1 = *(const float4*)(xb + (size_t)i*1024 + c + 4);
    uint4 o;
    o.x = pk2(a0.x*b0.x, a0.y*b0.y);
    o.y = pk2(a0.z*b0.z, a0.w*b0.w);
    o.z = pk2(a1.x*b1.x, a1.y*b1.y);
    o.w = pk2(a1.z*b1.z, a1.w*b1.w);
    *(uint4*)(pbuf + (size_t)z*pz + (size_t)row*1024 + c) = o;
  }
}

// ---------- staging: ROWS x 64 k (bf16) via global_load_lds, XOR-swizzled k-blocks
template<int ROWS>
DEVFN void stage_gl(const u16* __restrict__ g0, u16* lds0, int tid){
  constexpr int IT = ROWS/32;
  int w = tid>>6, lane = tid&63;
  #pragma unroll
  for(int i=0;i<IT;i++){
    int p  = (w*IT+i)*64 + lane;
    int r  = p>>3;
    int kb = (p&7) ^ (r&7);
    const u16* g = g0 + ((size_t)r<<10) + (kb<<3);
    u16* l = lds0 + (size_t)(w*IT+i)*512;
    __builtin_amdgcn_global_load_lds((const __attribute__((address_space(1))) u32*)g,
                                     (__attribute__((address_space(3))) u32*)l, 16, 0, 0);
  }
}

// ---------- GEMM tile body: TMxTN, BK=64, K=1024 (16 iters), 4 waves (2x2)
// AMODE: 0 = single source (A += z*a0z) ; 2 = z-select (z? A1,B1,bias1 : A0,B0,bias0)
// EPI: 0 = relu+bias -> bf16 out (+z*oz), LDS-staged coalesced write
//      2 = logit: relu+bias tile dot aux(=Wa3), lane-reduced, atomicAdd ((float*)out)[(aux2+z)*4096+row]
//      3 = split-K final: atomicAdd fp32 acc/3; z==0 adds (aux(x)+bias0+bias1)/3; row<aux2 guard
template<int AMODE, int EPI, int TM, int TN>
DEVFN void gemm_tile(
    const u16* __restrict__ A0, const u16* __restrict__ B0,
    const u16* __restrict__ A1, const u16* __restrict__ B1,
    const float* __restrict__ bias0, const float* __restrict__ bias1,
    const float* __restrict__ aux, void* __restrict__ out,
    long a0z, long oz, int ldo, int aux2,
    int m0, int n0, int z, u16* smem, int tid)
{
  constexpr int MB = TM/32, NB = TN/32;
  u16* As = smem;
  u16* Bs = smem + TM*64;

  const u16* Abase0;
  const u16* Bbase0;
  if(AMODE==2){
    Abase0 = (z ? A1 : A0) + (size_t)m0*1024;
    Bbase0 = (z ? B1 : B0) + (size_t)n0*1024;
  } else {
    Abase0 = A0 + (size_t)z*a0z + (size_t)m0*1024;
    Bbase0 = B0 + (size_t)n0*1024;
  }

  f32x4 acc[MB][NB];
  #pragma unroll
  for(int a=0;a<MB;a++)
    #pragma unroll
    for(int b=0;b<NB;b++) acc[a][b] = (f32x4){0.f,0.f,0.f,0.f};

  int w = tid>>6, lane = tid&63, quad = lane>>4, l15 = lane&15;
  int wr = (w>>1)*(TM/2), wc = (w&1)*(TN/2);

  for(int kk=0; kk<16; kk++){
    int k0 = kk << 6;
    __syncthreads();
    stage_gl<TM>(Abase0 + k0, As, tid);
    stage_gl<TN>(Bbase0 + k0, Bs, tid);
    __syncthreads();
    #pragma unroll
    for(int kq=0; kq<2; kq++){
      int kbl = kq*4 + quad;
      bf16x8 af[MB], bfv[NB];
      #pragma unroll
      for(int t=0;t<MB;t++){
        int rr = wr + t*16 + l15;
        af[t] = *(const bf16x8*)(As + rr*64 + ((kbl ^ (rr&7))<<3));
      }
      #pragma unroll
      for(int t=0;t<NB;t++){
        int cc = wc + t*16 + l15;
        bfv[t] = *(const bf16x8*)(Bs + cc*64 + ((kbl ^ (cc&7))<<3));
      }
      #pragma unroll
      for(int rt=0;rt<MB;rt++)
        #pragma unroll
        for(int ct=0;ct<NB;ct++)
          acc[rt][ct] = __builtin_amdgcn_mfma_f32_16x16x32_bf16(af[rt], bfv[ct], acc[rt][ct], 0,0,0);
    }
  }

  float bc[NB], w3[NB];
  #pragma unroll
  for(int ct=0;ct<NB;ct++){
    int colg = n0 + wc + ct*16 + l15;
    if(EPI==3){
      bc[ct] = (z==0) ? (bias0[colg] + bias1[colg]) : 0.f;
    } else {
      bc[ct] = (AMODE==2 && z) ? bias1[colg] : bias0[colg];
      if(EPI==2) w3[ct] = aux[colg];
    }
  }

  if(EPI==2){
    float part[MB][4];
    #pragma unroll
    for(int rt=0;rt<MB;rt++)
      #pragma unroll
      for(int r=0;r<4;r++) part[rt][r] = 0.f;
    #pragma unroll
    for(int rt=0;rt<MB;rt++)
      #pragma unroll
      for(int ct=0;ct<NB;ct++)
        #pragma unroll
        for(int r=0;r<4;r++)
          part[rt][r] += fmaxf(acc[rt][ct][r] + bc[ct], 0.f) * w3[ct];
    #pragma unroll
    for(int m=1;m<16;m<<=1)
      #pragma unroll
      for(int rt=0;rt<MB;rt++)
        #pragma unroll
        for(int r=0;r<4;r++)
          part[rt][r] += __shfl_xor(part[rt][r], m, 64);
    if(l15==0){
      float* lo = (float*)out + (size_t)(aux2 + z)*4096;
      #pragma unroll
      for(int rt=0;rt<MB;rt++)
        #pragma unroll
        for(int r=0;r<4;r++)
          atomicAdd(lo + (m0 + wr + rt*16 + quad*4 + r), part[rt][r]);
    }
    return;
  }

  if(EPI==3){
    const float third = 1.f/3.f;
    float* op = (float*)out;
    #pragma unroll
    for(int ct=0;ct<NB;ct++){
      int colg = n0 + wc + ct*16 + l15;
      #pragma unroll
      for(int rt=0;rt<MB;rt++){
        #pragma unroll
        for(int r=0;r<4;r++){
          int rowg = m0 + wr + rt*16 + quad*4 + r;
          if(rowg < aux2){
            float v = acc[rt][ct][r];
            if(z==0) v += aux[(size_t)rowg*1024 + colg] + bc[ct];
            atomicAdd(op + (size_t)rowg*ldo + colg, v*third);
          }
        }
      }
    }
    return;
  }

  // EPI==0: stage C tile in LDS, then coalesced 16B stores
  __syncthreads();
  u16* Ct = smem;
  #pragma unroll
  for(int ct=0;ct<NB;ct++){
    int cl = wc + ct*16 + l15;
    #pragma unroll
    for(int rt=0;rt<MB;rt++){
      #pragma unroll
      for(int r=0;r<4;r++){
        int rl = wr + rt*16 + quad*4 + r;
        Ct[rl*TN + cl] = f2b(fmaxf(acc[rt][ct][r] + bc[ct], 0.f));
      }
    }
  }
  __syncthreads();
  u16* outp = (u16*)out + (size_t)z*oz;
  #pragma unroll
  for(int i=0;i<TM*TN/2048;i++){
    int q = i*256 + tid;
    int row = q/(TN/8), c16 = q%(TN/8);
    *(uint4*)(outp + (size_t)(m0+row)*ldo + n0 + c16*8) = *(const uint4*)(Ct + row*TN + c16*8);
  }
}

// ---------- k4 body: AddConv / ModulatorConv aggregation for (bz, i)
DEVFN void k4_body(const float* __restrict__ x,
    const float* __restrict__ adjA, const float* __restrict__ adjM,
    const float* __restrict__ logit, const float* __restrict__ ba3,
    u16* __restrict__ a_t, u16* __restrict__ m_t,
    int bz, int i, int t, float* ca, float* cm)
{
  if(t < 89){
    int tri = (t<=i) ? t*(179-t)/2 + (i-t) : i*(179-i)/2 + (t-i);
    float lg = logit[(size_t)bz*4096 + tri] + ba3[0];
    float sv = 1.f/(1.f + expf(-lg));
    ca[t] = sv * adjA[t*89 + i];
    cm[t] = adjM[t*89 + i];
  }
  __syncthreads();
  const float* xb = x + (size_t)bz*91136;
  int c0 = t*4;
  float aa0=0,aa1=0,aa2=0,aa3=0, am0=0,am1=0,am2=0,am3=0;
  #pragma unroll 8
  for(int j=0;j<89;j++){
    float4 xv = *(const float4*)(xb + (size_t)j*1024 + c0);
    float fa=ca[j], fm=cm[j];
    aa0+=fa*xv.x; aa1+=fa*xv.y; aa2+=fa*xv.z; aa3+=fa*xv.w;
    am0+=fm*xv.x; am1+=fm*xv.y; am2+=fm*xv.z; am3+=fm*xv.w;
  }
  float4 xi = *(const float4*)(xb + (size_t)i*1024 + c0);
  size_t ro = ((size_t)(bz*89 + i))*1024 + c0;
  ushort4 oa; oa.x=f2b(aa0); oa.y=f2b(aa1); oa.z=f2b(aa2); oa.w=f2b(aa3);
  ushort4 om;
  om.x=f2b(xi.x*am0); om.y=f2b(xi.y*am1);
  om.z=f2b(xi.z*am2); om.w=f2b(xi.w*am3);
  *(ushort4*)(a_t + ro) = oa;
  *(ushort4*)(m_t + ro) = om;
  __syncthreads();   // safe LDS reuse on next iteration
}

// ================= persistent mega-kernel: GRID blocks, 6 phases, own barrier =================
struct MegaArgs {
  TrPack tp;
  float* logit; float* dout;
  const float* X; const float* adjA; const float* adjM;
  const float *ba1,*ba2,*Wa3,*ba3,*badd1,*bmod1,*badd2,*bmod2;
  u16 *WaT1,*WaT2,*WaddT1,*WaddT2,*WmodT1,*WmodT2;
  u16 *a_t,*m_t,*ha,*hm,*pbuf,*h1;
  u32* cnt;
};

__global__ __launch_bounds__(256,3) void mega_k(MegaArgs a){
  __shared__ __align__(16) u16 smem[(128+128)*64];   // 32 KB, shared by all phases
  int b = blockIdx.x, tid = threadIdx.x;
  const long pz = (long)4096*1024, h1z = (long)4096*1024;

  // phase 0: prep (transposes + zeros + pgen), 23272 virtual ids
  for(int id=b; id<23272; id+=GRID)
    prep_body(a.tp, a.logit, a.dout, a.X, a.pbuf, pz, id, tid, smem);
  gbar(a.cnt, 1*GRID);

  // phase 1: layer1 GEMM, 2048 tiles; id keeps (z,m) fixed per block (+=GRID preserves v&255)
  for(int v=b; v<2048; v+=GRID){
    int n = v>>8, p = v&255, z = p>>5, m = p&31;
    gemm_tile<0,0,128,128>(a.pbuf, a.WaT1, nullptr,nullptr, a.ba1,nullptr, nullptr,
                           a.h1, pz, h1z, 1024, 0, m*128, n*128, z, smem, tid);
  }
  gbar(a.cnt, 2*GRID);

  // phase 2: layer2 + logit epilogue, 1024 tiles (TN=128)
  for(int v=b; v<1024; v+=GRID){
    int n = v>>8, p = v&255, z = p>>5, m = p&31;
    gemm_tile<0,2,128,128>(a.h1, a.WaT2, nullptr,nullptr, a.ba2,nullptr, a.Wa3,
                           a.logit, h1z, 0, 0, 0, m*128, n*128, z, smem, tid);
  }
  gbar(a.cnt, 3*GRID);

  // phase 3: k4 aggregation, 712 virtual ids
  for(int id=b; id<712; id+=GRID)
    k4_body(a.X, a.adjA, a.adjM, a.logit, a.ba3, a.a_t, a.m_t,
            id/89, id%89, tid, (float*)smem, (float*)smem + 96);
  gbar(a.cnt, 4*GRID);

  // phase 4: tail hidden GEMMs, 384 tiles (64x64, z-select)
  if(b < 384){
    int z = b/192, rem = b%192, m = rem%12, n = rem/12;
    gemm_tile<2,0,64,64>(a.a_t, a.WaddT1, a.m_t, a.WmodT1, a.badd1, a.bmod1, nullptr,
                         a.ha, 0, (long)768*1024, 1024, 0, m*64, n*64, z, smem, tid);
  }
  gbar(a.cnt, 5*GRID);

  // phase 5: final split-K, 384 tiles
  if(b < 384){
    int z = b/192, rem = b%192, m = rem%12, n = rem/12;
    gemm_tile<2,3,64,64>(a.ha, a.WaddT2, a.hm, a.WmodT2, a.badd2, a.bmod2, a.X,
                         a.dout, 0, 0, 1024, 712, m*64, n*64, z, smem, tid);
  }
}

// ================= legacy (non-flat workspace) fallback kernels =================
__global__ __launch_bounds__(256) void prep_k(TrPack pk, float* __restrict__ logit,
                                              float* __restrict__ dout,
                                              const float* __restrict__ x,
                                              u16* __restrict__ pbuf, long pz){
  __shared__ u16 tile[32*33];
  prep_body(pk, logit, dout, x, pbuf, pz, blockIdx.x, threadIdx.x, tile);
}

__global__ __launch_bounds__(256) void pgen_k(const float* __restrict__ x,
                                              u16* __restrict__ p, long pz, int bbase){
  int z = blockIdx.y, b = bbase + z, row = blockIdx.x;
  int j, i; row2ji(row < 4005 ? row : 0, &j, &i);
  const float* xb = x + (size_t)b*91136;
  int c = threadIdx.x*4;
  float4 a  = *(const float4*)(xb + (size_t)j*1024 + c);
  float4 bb = *(const float4*)(xb + (size_t)i*1024 + c);
  ushort4 o;
  o.x = f2b(a.x*bb.x); o.y = f2b(a.y*bb.y);
  o.z = f2b(a.z*bb.z); o.w = f2b(a.w*bb.w);
  *(ushort4*)(p + (size_t)z*pz + (size_t)row*1024 + c) = o;
}

template<int AMODE, int EPI, int TM, int TN, int MINW>
__global__ __launch_bounds__(256,MINW) void gemm_k(
    const u16* __restrict__ A0, const u16* __restrict__ B0,
    const u16* __restrict__ A1, const u16* __restrict__ B1,
    const float* __restrict__ bias0, const float* __restrict__ bias1,
    const float* __restrict__ aux, void* __restrict__ out,
    long a0z, long oz, int ldo, int aux2,
    int mmask, int mshift, int mlimit)
{
  int by = blockIdx.y;
  int m0 = (by & mmask)*TM, n0 = (by >> mshift)*TN, z = blockIdx.z;
  if(m0 >= mlimit) return;
  __shared__ __align__(16) u16 smem[(TM+TN)*64];
  gemm_tile<AMODE,EPI,TM,TN>(A0,B0,A1,B1,bias0,bias1,aux,out,a0z,oz,ldo,aux2,
                             m0,n0,z,smem,threadIdx.x);
}

__global__ __launch_bounds__(256) void k4_k(const float* __restrict__ x,
    const float* __restrict__ adjA, const float* __restrict__ adjM,
    const float* __restrict__ logit, const float* __restrict__ ba3,
    u16* __restrict__ a_t, u16* __restrict__ m_t)
{
  __shared__ float ca[96], cm[96];
  k4_body(x, adjA, adjM, logit, ba3, a_t, m_t, blockIdx.y, blockIdx.x, threadIdx.x, ca, cm);
}

extern "C" void kernel_launch(void* const* d_in, const int* in_sizes, int n_in,
                              void* d_out, int out_size, void* d_ws, size_t ws_size,
                              hipStream_t stream)
{
  const float* X     = (const float*)d_in[0];
  const float* adjA  = (const float*)d_in[1];
  const float* adjM  = (const float*)d_in[2];
  const float* Wa1   = (const float*)d_in[3];
  const float* ba1   = (const float*)d_in[4];
  const float* Wa2   = (const float*)d_in[5];
  const float* ba2   = (const float*)d_in[6];
  const float* Wa3   = (const float*)d_in[7];
  const float* ba3   = (const float*)d_in[8];
  const float* Wadd1 = (const float*)d_in[9];
  const float* badd1 = (const float*)d_in[10];
  const float* Wadd2 = (const float*)d_in[11];
  const float* badd2 = (const float*)d_in[12];
  const float* Wmod1 = (const float*)d_in[13];
  const float* bmod1 = (const float*)d_in[14];
  const float* Wmod2 = (const float*)d_in[15];
  const float* bmod2 = (const float*)d_in[16];

  char* w = (char*)d_ws;
  u16* WaT1   = (u16*)w; w += (size_t)1024*1024*2;
  u16* WaT2   = (u16*)w; w += (size_t)512*1024*2;
  u16* WaddT1 = (u16*)w; w += (size_t)1024*1024*2;
  u16* WaddT2 = (u16*)w; w += (size_t)1024*1024*2;
  u16* WmodT1 = (u16*)w; w += (size_t)1024*1024*2;
  u16* WmodT2 = (u16*)w; w += (size_t)1024*1024*2;
  float* logit= (float*)w; w += (size_t)8*4096*4;
  u16* a_t    = (u16*)w; w += (size_t)768*1024*2;
  u16* m_t    = (u16*)w; w += (size_t)768*1024*2;
  u16* ha     = (u16*)w; w += (size_t)768*1024*2;
  u16* hm     = (u16*)w; w += (size_t)768*1024*2;   // must stay adjacent to ha
  u32* cnt    = (u32*)w; w += 64;
  size_t fixed = (size_t)(w - (char*)d_ws);
  size_t per_p = (size_t)4096*1024*2, per_h1 = (size_t)4096*1024*2;
  bool flat = ws_size >= fixed + 8*(per_p + per_h1);
  int nb = flat ? 8 : 1;
  u16* pbuf = (u16*)w; w += per_p  * nb;
  u16* h1   = (u16*)w;

  TrPack tp;
  tp.a[0].src = Wa1;   tp.a[0].dst = WaT1;   tp.a[0].C = 1024;
  tp.a[1].src = Wa2;   tp.a[1].dst = WaT2;   tp.a[1].C = 512;
  tp.a[2].src = Wadd1; tp.a[2].dst = WaddT1; tp.a[2].C = 1024;
  tp.a[3].src = Wadd2; tp.a[3].dst = WaddT2; tp.a[3].C = 1024;
  tp.a[4].src = Wmod1; tp.a[4].dst = WmodT1; tp.a[4].C = 1024;
  tp.a[5].src = Wmod2; tp.a[5].dst = WmodT2; tp.a[5].C = 1024;

  long pz = (long)4096*1024, h1z = (long)4096*1024;

  if(flat){
    MegaArgs ma;
    ma.tp = tp; ma.logit = logit; ma.dout = (float*)d_out;
    ma.X = X; ma.adjA = adjA; ma.adjM = adjM;
    ma.ba1 = ba1; ma.ba2 = ba2; ma.Wa3 = Wa3; ma.ba3 = ba3;
    ma.badd1 = badd1; ma.bmod1 = bmod1; ma.badd2 = badd2; ma.bmod2 = bmod2;
    ma.WaT1 = WaT1; ma.WaT2 = WaT2; ma.WaddT1 = WaddT1; ma.WaddT2 = WaddT2;
    ma.WmodT1 = WmodT1; ma.WmodT2 = WmodT2;
    ma.a_t = a_t; ma.m_t = m_t; ma.ha = ha; ma.hm = hm; ma.pbuf = pbuf; ma.h1 = h1;
    ma.cnt = cnt;
    hipMemsetAsync(cnt, 0, 64, stream);
    mega_k<<<dim3(GRID), dim3(256), 0, stream>>>(ma);
    return;
  }

  // -------- legacy multi-launch fallback (per-batch workspace) --------
  prep_k<<<dim3(6888 + 2048*nb), 256, 0, stream>>>(tp, logit, (float*)d_out, X, pbuf, pz);
  for(int bb=0; bb<8; bb+=nb){
    if(bb) pgen_k<<<dim3(4096,nb),256,0,stream>>>(X, pbuf, pz, bb);
    gemm_k<0,0,128,128,3><<<dim3(1,256,nb),256,0,stream>>>(pbuf, WaT1, nullptr,nullptr, ba1,nullptr, nullptr,
                                                           h1, pz, h1z, 1024, 0, 31, 5, 4096);
    gemm_k<0,2,128,256,2><<<dim3(1,64,nb),256,0,stream>>>(h1, WaT2, nullptr,nullptr, ba2,nullptr, Wa3,
                                                          logit, h1z, 0, 0, bb, 31, 5, 4096);
  }
  k4_k<<<dim3(89,8),256,0,stream>>>(X, adjA, adjM, logit, ba3, a_t, m_t);
  gemm_k<2,0,64,64,4><<<dim3(1,256,2),256,0,stream>>>(a_t, WaddT1, m_t, WmodT1, badd1, bmod1, nullptr,
                                                      ha, 0, (long)768*1024, 1024, 0, 15, 4, 768);
  gemm_k<2,3,64,64,4><<<dim3(1,256,2),256,0,stream>>>(ha, WaddT2, hm, WmodT2, badd2, bmod2, X,
                                                      d_out, 0, 0, 1024, 712, 15, 4, 768);
}

// Round 12
// 269.524 us; speedup vs baseline: 3.9020x; 3.9020x over previous
//
#include <hip/hip_runtime.h>

typedef unsigned short u16;
typedef unsigned int   u32;
typedef __attribute__((ext_vector_type(8))) short bf16x8;
typedef __attribute__((ext_vector_type(4))) float f32x4;

#define DEVFN __device__ __forceinline__

DEVFN float b2f(u16 u){ u32 t=((u32)u)<<16; float f; __builtin_memcpy(&f,&t,4); return f; }
DEVFN u16 f2b(float f){ u32 t; __builtin_memcpy(&t,&f,4); t += 0x7fffu + ((t>>16)&1u); return (u16)(t>>16); }
DEVFN u32 pk2(float a, float b){ return (u32)f2b(a) | ((u32)f2b(b)<<16); }

// row -> (j,i) for upper-triangle pairs j<=i, N=89; base(j) = j*(179-j)/2
DEVFN void row2ji(int row, int* jj, int* ii){
  int j = (int)((179.0f - sqrtf(179.0f*179.0f - 8.0f*(float)row)) * 0.5f);
  if(j < 0) j = 0; if(j > 88) j = 88;
  while(j < 88 && (j+1)*(179-(j+1))/2 <= row) j++;
  while(j > 0 && j*(179-j)/2 > row) j--;
  *jj = j;
  *ii = j + (row - j*(179-j)/2);
}

struct TrArgs { const float* src; u16* dst; int C; };
struct TrPack { TrArgs a[6]; };

// ---------- fused prep:
// [0,6144)        weight transposes (32x32 tiles)
// [6144,6176)     logit zero (8*4096 fp32)
// [6176,6888)     d_out zero (712*1024 fp32)
// [6888,6888+2048*nb) pgen pairs: 2 rows per block, 16B stores
__global__ __launch_bounds__(256) void prep_k(TrPack pk, float* __restrict__ logit,
                                              float* __restrict__ dout,
                                              const float* __restrict__ x,
                                              u16* __restrict__ pbuf, long pz){
  __shared__ u16 tile[32][33];
  int id = blockIdx.x, tid = threadIdx.x;
  if(id < 6144){
    TrArgs t = pk.a[id>>10];
    int q = id & 1023;
    int bx = (q&31)*32, by = (q>>5)*32;
    if(bx >= t.C) return;
    int tx = tid&31, ty = tid>>5;
    #pragma unroll
    for(int yy=ty; yy<32; yy+=8) tile[yy][tx] = f2b(t.src[(size_t)(by+yy)*t.C + bx+tx]);
    __syncthreads();
    #pragma unroll
    for(int yy=ty; yy<32; yy+=8) t.dst[(size_t)(bx+yy)*1024 + by+tx] = tile[tx][yy];
  } else if(id < 6176){
    int idx = (id-6144)*1024 + tid*4;
    *(float4*)(logit + idx) = (float4){0.f,0.f,0.f,0.f};
  } else if(id < 6888){
    int idx = (id-6176)*1024 + tid*4;
    *(float4*)(dout + idx) = (float4){0.f,0.f,0.f,0.f};
  } else {
    int pid = id - 6888;
    int z = pid >> 11, rp = pid & 2047;
    int half = tid >> 7, t7 = tid & 127;
    int row = rp*2 + half;
    int j, i; row2ji(row < 4005 ? row : 0, &j, &i);
    const float* xb = x + (size_t)z*91136;
    int c = t7*8;
    float4 a0 = *(const float4*)(xb + (size_t)j*1024 + c);
    float4 a1 = *(const float4*)(xb + (size_t)j*1024 + c + 4);
    float4 b0 = *(const float4*)(xb + (size_t)i*1024 + c);
    float4 b1 = *(const float4*)(xb + (size_t)i*1024 + c + 4);
    uint4 o;
    o.x = pk2(a0.x*b0.x, a0.y*b0.y);
    o.y = pk2(a0.z*b0.z, a0.w*b0.w);
    o.z = pk2(a1.x*b1.x, a1.y*b1.y);
    o.w = pk2(a1.z*b1.z, a1.w*b1.w);
    *(uint4*)(pbuf + (size_t)z*pz + (size_t)row*1024 + c) = o;
  }
}

// standalone pgen for per-batch fallback iterations (1 row per block)
__global__ __launch_bounds__(256) void pgen_k(const float* __restrict__ x,
                                              u16* __restrict__ p, long pz, int bbase){
  int z = blockIdx.y, b = bbase + z, row = blockIdx.x;
  int j, i; row2ji(row < 4005 ? row : 0, &j, &i);
  const float* xb = x + (size_t)b*91136;
  int c = threadIdx.x*4;
  float4 a  = *(const float4*)(xb + (size_t)j*1024 + c);
  float4 bb = *(const float4*)(xb + (size_t)i*1024 + c);
  ushort4 o;
  o.x = f2b(a.x*bb.x); o.y = f2b(a.y*bb.y);
  o.z = f2b(a.z*bb.z); o.w = f2b(a.w*bb.w);
  *(ushort4*)(p + (size_t)z*pz + (size_t)row*1024 + c) = o;
}

// ---------- staging: ROWS x 64 k (bf16) via global_load_lds, XOR-swizzled k-blocks
template<int ROWS>
DEVFN void stage_gl(const u16* __restrict__ g0, u16* lds0, int tid){
  constexpr int IT = ROWS/32;
  int w = tid>>6, lane = tid&63;
  #pragma unroll
  for(int i=0;i<IT;i++){
    int p  = (w*IT+i)*64 + lane;
    int r  = p>>3;
    int kb = (p&7) ^ (r&7);
    const u16* g = g0 + ((size_t)r<<10) + (kb<<3);
    u16* l = lds0 + (size_t)(w*IT+i)*512;
    __builtin_amdgcn_global_load_lds((const __attribute__((address_space(1))) u32*)g,
                                     (__attribute__((address_space(3))) u32*)l, 16, 0, 0);
  }
}

// ---------- GEMM: tiles TMxTN, BK=64, 4 waves (2x2); blockIdx.y = n*mblkpad + m
// AMODE: 0 = single source (z = batch, A += z*a0z) ; 2 = z-select (z? A1,B1,bias1 : A0,B0,bias0)
// EPI:   0 = relu+bias -> bf16 out (+z*oz), LDS-staged coalesced write (requires TM*TN <= (TM+TN)*64)
//        2 = logit: relu+bias tile dot aux(=Wa3), lane-reduced, atomicAdd ((float*)out)[(aux2+z)*4096+row]
//        3 = split-K final: atomicAdd fp32 acc/3 into out; z==0 also adds (aux(x)+bias0+bias1)/3; row<aux2 guard
// MINW: min waves per EU for __launch_bounds__
template<int AMODE, int EPI, int TM, int TN, int MINW>
__global__ __launch_bounds__(256,MINW) void gemm_k(
    const u16* __restrict__ A0, const u16* __restrict__ B0,
    const u16* __restrict__ A1, const u16* __restrict__ B1,
    const float* __restrict__ bias0, const float* __restrict__ bias1,
    const float* __restrict__ aux,
    void* __restrict__ out,
    long a0z, long oz, int ldo, int aux2, int kiters,
    int mmask, int mshift, int mlimit)
{
  constexpr int MB = TM/32, NB = TN/32;
  int by = blockIdx.y;
  int m0 = (by & mmask)*TM, n0 = (by >> mshift)*TN, z = blockIdx.z;
  if(m0 >= mlimit) return;   // block-uniform: safe before barriers

  __shared__ __align__(16) u16 smem[TM*64 + TN*64];
  u16* As = smem;
  u16* Bs = smem + TM*64;
  int tid = threadIdx.x;

  const u16* Abase0;
  const u16* Bbase0;
  if(AMODE==2){
    Abase0 = (z ? A1 : A0) + (size_t)m0*1024;
    Bbase0 = (z ? B1 : B0) + (size_t)n0*1024;
  } else {
    Abase0 = A0 + (size_t)z*a0z + (size_t)m0*1024;
    Bbase0 = B0 + (size_t)n0*1024;
  }

  f32x4 acc[MB][NB];
  #pragma unroll
  for(int a=0;a<MB;a++)
    #pragma unroll
    for(int b=0;b<NB;b++) acc[a][b] = (f32x4){0.f,0.f,0.f,0.f};

  int w = tid>>6, lane = tid&63, quad = lane>>4, l15 = lane&15;
  int wr = (w>>1)*(TM/2), wc = (w&1)*(TN/2);

  for(int kk=0; kk<kiters; kk++){
    int k0 = (kk & 15) << 6;
    const u16* Ab = Abase0 + k0;
    const u16* Bb = Bbase0 + k0;
    __syncthreads();
    stage_gl<TM>(Ab, As, tid);
    stage_gl<TN>(Bb, Bs, tid);
    __syncthreads();
    #pragma unroll
    for(int kq=0; kq<2; kq++){
      int kbl = kq*4 + quad;
      bf16x8 af[MB], bfv[NB];
      #pragma unroll
      for(int t=0;t<MB;t++){
        int rr = wr + t*16 + l15;
        af[t] = *(const bf16x8*)(As + rr*64 + ((kbl ^ (rr&7))<<3));
      }
      #pragma unroll
      for(int t=0;t<NB;t++){
        int cc = wc + t*16 + l15;
        bfv[t] = *(const bf16x8*)(Bs + cc*64 + ((kbl ^ (cc&7))<<3));
      }
      #pragma unroll
      for(int rt=0;rt<MB;rt++)
        #pragma unroll
        for(int ct=0;ct<NB;ct++)
          acc[rt][ct] = __builtin_amdgcn_mfma_f32_16x16x32_bf16(af[rt], bfv[ct], acc[rt][ct], 0,0,0);
    }
  }

  float bc[NB], w3[NB];
  #pragma unroll
  for(int ct=0;ct<NB;ct++){
    int colg = n0 + wc + ct*16 + l15;
    if(EPI==3){
      bc[ct] = (z==0) ? (bias0[colg] + bias1[colg]) : 0.f;
    } else {
      bc[ct] = (AMODE==2 && z) ? bias1[colg] : bias0[colg];
      if(EPI==2) w3[ct] = aux[colg];
    }
  }

  if(EPI==2){
    float part[MB][4];
    #pragma unroll
    for(int rt=0;rt<MB;rt++)
      #pragma unroll
      for(int r=0;r<4;r++) part[rt][r] = 0.f;
    #pragma unroll
    for(int rt=0;rt<MB;rt++)
      #pragma unroll
      for(int ct=0;ct<NB;ct++)
        #pragma unroll
        for(int r=0;r<4;r++)
          part[rt][r] += fmaxf(acc[rt][ct][r] + bc[ct], 0.f) * w3[ct];
    #pragma unroll
    for(int m=1;m<16;m<<=1)
      #pragma unroll
      for(int rt=0;rt<MB;rt++)
        #pragma unroll
        for(int r=0;r<4;r++)
          part[rt][r] += __shfl_xor(part[rt][r], m, 64);
    if(l15==0){
      float* lo = (float*)out + (size_t)(aux2 + z)*4096;
      #pragma unroll
      for(int rt=0;rt<MB;rt++)
        #pragma unroll
        for(int r=0;r<4;r++)
          atomicAdd(lo + (m0 + wr + rt*16 + quad*4 + r), part[rt][r]);
    }
    return;
  }

  if(EPI==3){
    const float third = 1.f/3.f;
    float* op = (float*)out;
    #pragma unroll
    for(int ct=0;ct<NB;ct++){
      int colg = n0 + wc + ct*16 + l15;
      #pragma unroll
      for(int rt=0;rt<MB;rt++){
        #pragma unroll
        for(int r=0;r<4;r++){
          int rowg = m0 + wr + rt*16 + quad*4 + r;
          if(rowg < aux2){
            float v = acc[rt][ct][r];
            if(z==0) v += aux[(size_t)rowg*1024 + colg] + bc[ct];
            atomicAdd(op + (size_t)rowg*ldo + colg, v*third);
          }
        }
      }
    }
    return;
  }

  // EPI==0: stage C tile (TM x TN bf16) in LDS, then coalesced 16B stores
  __syncthreads();
  u16* Ct = smem;
  #pragma unroll
  for(int ct=0;ct<NB;ct++){
    int cl = wc + ct*16 + l15;
    #pragma unroll
    for(int rt=0;rt<MB;rt++){
      #pragma unroll
      for(int r=0;r<4;r++){
        int rl = wr + rt*16 + quad*4 + r;
        Ct[rl*TN + cl] = f2b(fmaxf(acc[rt][ct][r] + bc[ct], 0.f));
      }
    }
  }
  __syncthreads();
  u16* outp = (u16*)out + (size_t)z*oz;
  #pragma unroll
  for(int i=0;i<TM*TN/2048;i++){
    int q = i*256 + tid;
    int row = q/(TN/8), c16 = q%(TN/8);
    *(uint4*)(outp + (size_t)(m0+row)*ldo + n0 + c16*8) = *(const uint4*)(Ct + row*TN + c16*8);
  }
}

// ---------- AddConv / ModulatorConv aggregation -> a_t, m_t (bf16); sigmoid applied here
__global__ __launch_bounds__(256) void k4_k(const float* __restrict__ x,
    const float* __restrict__ adjA, const float* __restrict__ adjM,
    const float* __restrict__ logit, const float* __restrict__ ba3,
    u16* __restrict__ a_t, u16* __restrict__ m_t)
{
  int b = blockIdx.y, i = blockIdx.x, t = threadIdx.x;
  __shared__ float ca[89], cm[89];
  if(t < 89){
    int tri = (t<=i) ? t*(179-t)/2 + (i-t) : i*(179-i)/2 + (t-i);
    float lg = logit[(size_t)b*4096 + tri] + ba3[0];
    float sv = 1.f/(1.f + expf(-lg));
    ca[t] = sv * adjA[t*89 + i];
    cm[t] = adjM[t*89 + i];
  }
  __syncthreads();
  const float* xb = x + (size_t)b*91136;
  int c0 = t*4;
  float aa0=0,aa1=0,aa2=0,aa3=0, am0=0,am1=0,am2=0,am3=0;
  #pragma unroll 8
  for(int j=0;j<89;j++){
    float4 xv = *(const float4*)(xb + (size_t)j*1024 + c0);
    float fa=ca[j], fm=cm[j];
    aa0+=fa*xv.x; aa1+=fa*xv.y; aa2+=fa*xv.z; aa3+=fa*xv.w;
    am0+=fm*xv.x; am1+=fm*xv.y; am2+=fm*xv.z; am3+=fm*xv.w;
  }
  float4 xi = *(const float4*)(xb + (size_t)i*1024 + c0);
  size_t ro = ((size_t)(b*89 + i))*1024 + c0;
  ushort4 oa; oa.x=f2b(aa0); oa.y=f2b(aa1); oa.z=f2b(aa2); oa.w=f2b(aa3);
  ushort4 om;
  om.x=f2b(xi.x*am0); om.y=f2b(xi.y*am1);
  om.z=f2b(xi.z*am2); om.w=f2b(xi.w*am3);
  *(ushort4*)(a_t + ro) = oa;
  *(ushort4*)(m_t + ro) = om;
}

extern "C" void kernel_launch(void* const* d_in, const int* in_sizes, int n_in,
                              void* d_out, int out_size, void* d_ws, size_t ws_size,
                              hipStream_t stream)
{
  const float* X     = (const float*)d_in[0];
  const float* adjA  = (const float*)d_in[1];
  const float* adjM  = (const float*)d_in[2];
  const float* Wa1   = (const float*)d_in[3];
  const float* ba1   = (const float*)d_in[4];
  const float* Wa2   = (const float*)d_in[5];
  const float* ba2   = (const float*)d_in[6];
  const float* Wa3   = (const float*)d_in[7];
  const float* ba3   = (const float*)d_in[8];
  const float* Wadd1 = (const float*)d_in[9];
  const float* badd1 = (const float*)d_in[10];
  const float* Wadd2 = (const float*)d_in[11];
  const float* badd2 = (const float*)d_in[12];
  const float* Wmod1 = (const float*)d_in[13];
  const float* bmod1 = (const float*)d_in[14];
  const float* Wmod2 = (const float*)d_in[15];
  const float* bmod2 = (const float*)d_in[16];

  char* w = (char*)d_ws;
  u16* WaT1   = (u16*)w; w += (size_t)1024*1024*2;
  u16* WaT2   = (u16*)w; w += (size_t)512*1024*2;
  u16* WaddT1 = (u16*)w; w += (size_t)1024*1024*2;
  u16* WaddT2 = (u16*)w; w += (size_t)1024*1024*2;
  u16* WmodT1 = (u16*)w; w += (size_t)1024*1024*2;
  u16* WmodT2 = (u16*)w; w += (size_t)1024*1024*2;
  float* logit= (float*)w; w += (size_t)8*4096*4;
  u16* a_t    = (u16*)w; w += (size_t)768*1024*2;
  u16* m_t    = (u16*)w; w += (size_t)768*1024*2;
  u16* ha     = (u16*)w; w += (size_t)768*1024*2;
  u16* hm     = (u16*)w; w += (size_t)768*1024*2;   // must stay adjacent to ha
  size_t fixed = (size_t)(w - (char*)d_ws);
  size_t per_p = (size_t)4096*1024*2, per_h1 = (size_t)4096*1024*2;
  bool flat = ws_size >= fixed + 8*(per_p + per_h1);
  int nb = flat ? 8 : 1;
  u16* pbuf = (u16*)w; w += per_p  * nb;
  u16* h1   = (u16*)w;

  TrPack tp;
  tp.a[0].src = Wa1;   tp.a[0].dst = WaT1;   tp.a[0].C = 1024;
  tp.a[1].src = Wa2;   tp.a[1].dst = WaT2;   tp.a[1].C = 512;
  tp.a[2].src = Wadd1; tp.a[2].dst = WaddT1; tp.a[2].C = 1024;
  tp.a[3].src = Wadd2; tp.a[3].dst = WaddT2; tp.a[3].C = 1024;
  tp.a[4].src = Wmod1; tp.a[4].dst = WmodT1; tp.a[4].C = 1024;
  tp.a[5].src = Wmod2; tp.a[5].dst = WmodT2; tp.a[5].C = 1024;

  long pz = 4096*1024, h1z = 4096*1024;
  prep_k<<<dim3(6888 + 2048*nb), 256, 0, stream>>>(tp, logit, (float*)d_out, X, pbuf, pz);

  for(int bb=0; bb<8; bb+=nb){
    if(bb) pgen_k<<<dim3(4096,nb),256,0,stream>>>(X, pbuf, pz, bb);
    // layer1: M=4096 (32 mblk), N=1024 (8 nblk @ TN=128): y = n*32 + m; 3 blocks/CU
    gemm_k<0,0,128,128,3><<<dim3(1,256,nb),256,0,stream>>>(pbuf, WaT1, nullptr,nullptr, ba1,nullptr, nullptr,
                                                           h1, pz, h1z, 1024, 4096, 16, 31, 5, 4096);
    // layer2 + logit epilogue: M=4096 (32 mblk), N=512 (2 nblk @ TN=256)
    gemm_k<0,2,128,256,2><<<dim3(1,64,nb),256,0,stream>>>(h1, WaT2, nullptr,nullptr, ba2,nullptr, Wa3,
                                                          logit, h1z, 0, 0, bb, 16, 31, 5, 4096);
  }
  k4_k<<<dim3(89,8),256,0,stream>>>(X, adjA, adjM, logit, ba3, a_t, m_t);
  // tail hidden GEMMs (64x64 tiles, 4 blocks/CU): z=0 -> a_t@Wadd1 -> ha ; z=1 -> m_t@Wmod1 -> hm
  gemm_k<2,0,64,64,4><<<dim3(1,256,2),256,0,stream>>>(a_t, WaddT1, m_t, WmodT1, badd1, bmod1, nullptr,
                                                      ha, 0, (long)768*1024, 1024, 768, 16, 15, 4, 768);
  // final split-K (64x64): d_out zeroed in prep; z=0: ha@WaddT2 (+x+biases)/3, z=1: hm@WmodT2 /3
  gemm_k<2,3,64,64,4><<<dim3(1,256,2),256,0,stream>>>(ha, WaddT2, hm, WmodT2, badd2, bmod2, X,
                                                      d_out, 0, 0, 1024, 712, 16, 15, 4, 768);
}